// Round 2
// baseline (167.181 us; speedup 1.0000x reference)
//
#include <hip/hip_runtime.h>
#include <hip/hip_bf16.h>

#define NQ 2048
#define NO 2048
#define DL 64
#define NCHUNK 16   // o-chunk blocks per q-group (global partials)

// workspace layout (float offsets)
constexpr size_t OFF_U  = 0;                          // NQ*64   : U[q][l] (b1 folded)
constexpr size_t OFF_T  = OFF_U  + (size_t)NQ * 64;   // NO*68   : T[o][0..63], pos_o at [64..66]
constexpr size_t OFF_V  = OFF_T  + (size_t)NO * 68;   // NO*64   : V[o][l] (bv folded)
constexpr size_t OFF_PQ = OFF_V  + (size_t)NO * 64;   // NQ*4    : pos_q (padded to 4)
constexpr size_t OFF_W2 = OFF_PQ + (size_t)NQ * 4;    // 64      : W2
constexpr size_t OFF_PH = OFF_W2 + 64;                // NCHUNK*NQ*64 : partial h
constexpr size_t OFF_PM = OFF_PH + (size_t)NCHUNK * NQ * 64; // NCHUNK*NQ : partial max
constexpr size_t OFF_PS = OFF_PM + (size_t)NCHUNK * NQ;      // NCHUNK*NQ : partial sum
// total ≈ 2.57M floats ≈ 10.3 MB

// ---------------------------------------------------------------------------
// Prep: U[q][l], T[o][l] (+pos_o), V[o][l], pos_q, W2.   gid -> i=row, l=latent
// ---------------------------------------------------------------------------
__global__ void gano_prep(const float* __restrict__ h_obs,
                          const float* __restrict__ pos_obs,
                          const float* __restrict__ pos_query,
                          const float* __restrict__ W1,
                          const float* __restrict__ b1,
                          const float* __restrict__ W2,
                          const float* __restrict__ Wv,
                          const float* __restrict__ bv,
                          float* __restrict__ ws) {
    int gid = blockIdx.x * 256 + threadIdx.x;
    int i = gid >> 6;
    int l = gid & 63;
    if (i >= NQ) return;

    float w1[9];
#pragma unroll
    for (int e = 0; e < 9; ++e) w1[e] = W1[e * 64 + l];

    // U = b1 + pos_q @ (W1[0:3] + W1[6:9])
    float pq0 = pos_query[i * 3 + 0];
    float pq1 = pos_query[i * 3 + 1];
    float pq2 = pos_query[i * 3 + 2];
    float Uv = b1[l] + pq0 * (w1[0] + w1[6]) + pq1 * (w1[1] + w1[7]) + pq2 * (w1[2] + w1[8]);
    ws[OFF_U + (size_t)i * 64 + l] = Uv;

    // T = pos_o @ (W1[3:6] - W1[6:9])
    float po0 = pos_obs[i * 3 + 0];
    float po1 = pos_obs[i * 3 + 1];
    float po2 = pos_obs[i * 3 + 2];
    float Tv = po0 * (w1[3] - w1[6]) + po1 * (w1[4] - w1[7]) + po2 * (w1[5] - w1[8]);
    ws[OFF_T + (size_t)i * 68 + l] = Tv;
    if (l < 3) {
        ws[OFF_T + (size_t)i * 68 + 64 + l] = pos_obs[i * 3 + l];
        ws[OFF_PQ + (size_t)i * 4 + l]      = pos_query[i * 3 + l];
    }
    if (l == 3) ws[OFF_PQ + (size_t)i * 4 + 3] = 0.f;

    // V = bv + h_obs @ Wv
    float acc = bv[l];
#pragma unroll 8
    for (int k = 0; k < 64; ++k)
        acc += h_obs[i * 64 + k] * Wv[k * 64 + l];
    ws[OFF_V + (size_t)i * 64 + l] = acc;

    if (i == 0) ws[OFF_W2 + l] = W2[l];  // W2 shape (64,1)
}

// ---------------------------------------------------------------------------
// Main: lanes = queries. grid = 32 q-groups * NCHUNK chunk-blocks.
// Each block: 4 waves over the same 64 queries, o-subranges of 32 each.
// Online softmax per lane; wave partials merged in LDS; block partial -> ws.
// ---------------------------------------------------------------------------
__global__ __launch_bounds__(256, 2) void gano_main(const float* __restrict__ ws,
                                                    float* __restrict__ wsp) {
    const int tid  = threadIdx.x;
    const int lane = tid & 63;
    const int wave = __builtin_amdgcn_readfirstlane(tid >> 6);
    const int group = blockIdx.x >> 4;        // 0..31
    const int chunk = blockIdx.x & (NCHUNK - 1);
    const int q = group * 64 + lane;

    // per-lane U row, W2 (broadcast), pos_q
    float u[64], w2v[64], h[64];
    {
        const float4* up = (const float4*)(ws + OFF_U + (size_t)q * 64);
        const float4* wp = (const float4*)(ws + OFF_W2);
#pragma unroll
        for (int j = 0; j < 16; ++j) {
            float4 a = up[j];
            u[4 * j + 0] = a.x; u[4 * j + 1] = a.y; u[4 * j + 2] = a.z; u[4 * j + 3] = a.w;
            float4 b = wp[j];
            w2v[4 * j + 0] = b.x; w2v[4 * j + 1] = b.y; w2v[4 * j + 2] = b.z; w2v[4 * j + 3] = b.w;
        }
    }
    float4 pqv = *(const float4*)(ws + OFF_PQ + (size_t)q * 4);
#pragma unroll
    for (int l = 0; l < 64; ++l) h[l] = 0.f;
    float m = -1e30f, s = 0.f;

    const int o0 = chunk * (NO / NCHUNK) + wave * 32;   // 32 o's per wave
    for (int i = 0; i < 32; ++i) {
        const float* __restrict__ trow = ws + OFF_T + (size_t)(o0 + i) * 68;  // wave-uniform
        float a0 = 0.f, a1 = 0.f, a2 = 0.f, a3 = 0.f;
#pragma unroll
        for (int l = 0; l < 64; l += 4) {
            a0 += w2v[l + 0] * fmaxf(u[l + 0] + trow[l + 0], 0.f);
            a1 += w2v[l + 1] * fmaxf(u[l + 1] + trow[l + 1], 0.f);
            a2 += w2v[l + 2] * fmaxf(u[l + 2] + trow[l + 2], 0.f);
            a3 += w2v[l + 3] * fmaxf(u[l + 3] + trow[l + 3], 0.f);
        }
        float logit = (a0 + a1) + (a2 + a3);
        // radius mask: dist^2 > 0.25 -> finite -inf sentinel (no inf-inf NaN)
        float d0 = pqv.x - trow[64];
        float d1 = pqv.y - trow[65];
        float d2 = pqv.z - trow[66];
        float dd = d0 * d0 + d1 * d1 + d2 * d2;
        logit = (dd > 0.25f) ? -1e30f : logit;
        // online softmax; masked-only prefix wiped by sc=exp(-1e30-m_real)=0
        float mn = fmaxf(m, logit);
        float sc = __expf(m - mn);
        float e  = __expf(logit - mn);
        s = s * sc + e;
        m = mn;
        const float* __restrict__ vrow = ws + OFF_V + (size_t)(o0 + i) * 64;  // wave-uniform
#pragma unroll
        for (int l = 0; l < 64; ++l) h[l] = h[l] * sc + e * vrow[l];
    }

    // ---- intra-block combine (waves 1..3 -> LDS, wave 0 merges) ----
    __shared__ float buf[3 * 64 * 66];   // 50.7 KB
    if (wave >= 1) {
        float* b = buf + (size_t)(wave - 1) * 64 * 66 + lane * 66;
#pragma unroll
        for (int l = 0; l < 64; ++l) b[l] = h[l];
        b[64] = m; b[65] = s;
    }
    __syncthreads();
    if (wave == 0) {
        for (int c = 0; c < 3; ++c) {
            const float* b = buf + (size_t)c * 64 * 66 + lane * 66;
            float mc = b[64], sc2 = b[65];
            float M  = fmaxf(m, mc);
            float e1 = __expf(m - M);
            float e2 = __expf(mc - M);
            s = s * e1 + sc2 * e2;
#pragma unroll
            for (int l = 0; l < 64; ++l) h[l] = h[l] * e1 + b[l] * e2;
            m = M;
        }
        float* b0 = buf + lane * 66;     // reads of c=0 region all precede this
#pragma unroll
        for (int l = 0; l < 64; ++l) b0[l] = h[l];
        b0[64] = m; b0[65] = s;
    }
    __syncthreads();

    // ---- write block partial, coalesced: wave w -> 16 q's, lane = latent ----
    float* Ph = wsp + OFF_PH;
    float* Pm = wsp + OFF_PM;
    float* Ps = wsp + OFF_PS;
    const int l = lane;
    for (int j = 0; j < 16; ++j) {
        int ql = wave * 16 + j;
        const float* b = buf + (size_t)ql * 66;
        int qq = group * 64 + ql;
        Ph[((size_t)chunk * NQ + qq) * 64 + l] = b[l];
        if (l == 0) {
            Pm[(size_t)chunk * NQ + qq] = b[64];
            Ps[(size_t)chunk * NQ + qq] = b[65];
        }
    }
}

// ---------------------------------------------------------------------------
// Combine NCHUNK partials per query, normalize, emit f32.  gid -> q,l
// ---------------------------------------------------------------------------
__global__ void gano_combine(const float* __restrict__ ws, float* __restrict__ out) {
    int gid = blockIdx.x * 256 + threadIdx.x;
    int q = gid >> 6;
    int l = gid & 63;
    if (q >= NQ) return;
    const float* Ph = ws + OFF_PH;
    const float* Pm = ws + OFF_PM;
    const float* Ps = ws + OFF_PS;

    float M = -1e30f;
#pragma unroll
    for (int c = 0; c < NCHUNK; ++c) M = fmaxf(M, Pm[(size_t)c * NQ + q]);
    float S = 0.f, hv = 0.f;
#pragma unroll
    for (int c = 0; c < NCHUNK; ++c) {
        float e = __expf(Pm[(size_t)c * NQ + q] - M);
        S  += Ps[(size_t)c * NQ + q] * e;
        hv += Ph[((size_t)c * NQ + q) * 64 + l] * e;
    }
    out[gid] = hv / S;
}

// ---------------------------------------------------------------------------
extern "C" void kernel_launch(void* const* d_in, const int* in_sizes, int n_in,
                              void* d_out, int out_size, void* d_ws, size_t ws_size,
                              hipStream_t stream) {
    const float* h_obs     = (const float*)d_in[0];
    // d_in[1] = x_obs (unused by reference)
    const float* pos_obs   = (const float*)d_in[2];
    const float* pos_query = (const float*)d_in[3];
    const float* W1        = (const float*)d_in[4];
    const float* b1        = (const float*)d_in[5];
    const float* W2        = (const float*)d_in[6];
    // d_in[7] = b2: constant shift, cancels in softmax
    const float* Wv        = (const float*)d_in[8];
    const float* bv        = (const float*)d_in[9];
    float* ws  = (float*)d_ws;
    float* out = (float*)d_out;

    gano_prep<<<dim3((NQ * 64) / 256), dim3(256), 0, stream>>>(
        h_obs, pos_obs, pos_query, W1, b1, W2, Wv, bv, ws);
    gano_main<<<dim3(32 * NCHUNK), dim3(256), 0, stream>>>(ws, ws);
    gano_combine<<<dim3((NQ * 64) / 256), dim3(256), 0, stream>>>(ws, out);
}